// Round 1
// baseline (410.495 us; speedup 1.0000x reference)
//
#include <hip/hip_runtime.h>

#define Bz 32
#define Nn 510
#define Dd 64
#define Hh 4
#define HD_ 256
#define ALPHA_ 0.1f
#define LNEPS 1e-5f
#define SLOPE 0.01f
#define NEG_INF -3.0e38f

__device__ inline float wredsum(float v) {
  #pragma unroll
  for (int off = 32; off; off >>= 1) v += __shfl_xor(v, off, 64);
  return v;
}
__device__ inline float wredmax(float v) {
  #pragma unroll
  for (int off = 32; off; off >>= 1) v = fmaxf(v, __shfl_xor(v, off, 64));
  return v;
}

// K1: xt[b,n,h*64+d] = x[b,n,:] @ W[:, h*64+d].  Grid (16 rowtiles, 32 b, 2 colhalves)
__global__ __launch_bounds__(256) void k1_xt(const float* __restrict__ x,
                                             const float* __restrict__ W,
                                             float* __restrict__ xt) {
  __shared__ float Wl[64][132];
  __shared__ float xr[32][68];
  const int t = threadIdx.x;
  const int rt = blockIdx.x;
  const int b = blockIdx.y;
  const int ch = blockIdx.z;
  #pragma unroll
  for (int k = 0; k < 8; k++) {
    int f = t + k * 256;
    int kr = f >> 5;
    int c = (f & 31) * 4;
    float4 v = *(const float4*)&W[kr * HD_ + ch * 128 + c];
    *(float4*)&Wl[kr][c] = v;
  }
  #pragma unroll
  for (int k = 0; k < 2; k++) {
    int f = t + k * 256;
    int r = f >> 4;
    int c = (f & 15) * 4;
    int row = rt * 32 + r;
    float4 v = make_float4(0.f, 0.f, 0.f, 0.f);
    if (row < Nn) v = *(const float4*)&x[(b * Nn + row) * Dd + c];
    *(float4*)&xr[r][c] = v;
  }
  __syncthreads();
  const int tr = t >> 5, tc = t & 31;
  const int rb = tr * 4, c0 = tc * 4;
  float acc[4][4] = {};
  #pragma unroll
  for (int k4 = 0; k4 < 16; k4++) {
    float4 xv[4];
    #pragma unroll
    for (int r = 0; r < 4; r++) xv[r] = *(float4*)&xr[rb + r][k4 * 4];
    #pragma unroll
    for (int kk = 0; kk < 4; kk++) {
      float4 wv = *(float4*)&Wl[k4 * 4 + kk][c0];
      #pragma unroll
      for (int r = 0; r < 4; r++) {
        float xs = (&xv[r].x)[kk];
        acc[r][0] = fmaf(xs, wv.x, acc[r][0]);
        acc[r][1] = fmaf(xs, wv.y, acc[r][1]);
        acc[r][2] = fmaf(xs, wv.z, acc[r][2]);
        acc[r][3] = fmaf(xs, wv.w, acc[r][3]);
      }
    }
  }
  #pragma unroll
  for (int r = 0; r < 4; r++) {
    int row = rt * 32 + rb + r;
    if (row < Nn) {
      *(float4*)&xt[(b * Nn + row) * HD_ + ch * 128 + c0] =
          make_float4(acc[r][0], acc[r][1], acc[r][2], acc[r][3]);
    }
  }
}

// K1b: s_i[b,h,n] = sum_d xt[b,n,h,d]*w1[h,d];  s_j with w2.  One wave per (b,h,n).
__global__ __launch_bounds__(256) void k1b_s(const float* __restrict__ xt,
                                             const float* __restrict__ attw,
                                             float* __restrict__ si,
                                             float* __restrict__ sj) {
  const int t = threadIdx.x;
  const int idx = blockIdx.x * 4 + (t >> 6);
  const int lane = t & 63;
  const int n = idx % Nn;
  const int bh = idx / Nn;
  const int h = bh & 3;
  const int b = bh >> 2;
  float v = xt[(b * Nn + n) * HD_ + h * Dd + lane];
  float p1 = v * attw[h * 128 + lane];
  float p2 = v * attw[h * 128 + 64 + lane];
  p1 = wredsum(p1);
  p2 = wredsum(p2);
  if (lane == 0) { si[idx] = p1; sj[idx] = p2; }
}

// K2: per (b,i) row: recompute A_mean rows i-1..i+1 from s, 3x3 conv over
// [A_mean, causal], combine with alpha*leaky(e), softmax over j, write A.
__global__ __launch_bounds__(256) void k2_attn(const float* __restrict__ si,
                                               const float* __restrict__ sj,
                                               const float* __restrict__ causal,
                                               const float* __restrict__ convw,
                                               const float* __restrict__ convb,
                                               float* __restrict__ A) {
  __shared__ float amr[3][512];
  __shared__ float c3[3][512];
  __shared__ float red[4];
  const int t = threadIdx.x;
  const int i = blockIdx.x;
  const int b = blockIdx.y;
  for (int e = t; e < 1536; e += 256) {
    int row = e >> 9;
    int jj = e & 511;
    int iq = i + row - 1;
    int j = jj - 1;
    float am = 0.f, cz = 0.f;
    if (iq >= 0 && iq < Nn && j >= 0 && j < Nn) {
      float s = 0.f;
      #pragma unroll
      for (int h = 0; h < 4; h++) {
        float e2 = si[(b * 4 + h) * Nn + iq] + sj[(b * 4 + h) * Nn + j];
        s += (e2 >= 0.f) ? e2 : SLOPE * e2;
      }
      am = 0.25f * s;
      cz = causal[iq * Nn + j];
    }
    amr[row][jj] = am;
    c3[row][jj] = cz;
  }
  __syncthreads();
  const int j0 = 2 * t;            // this thread owns j0, j0+1
  const bool act = (j0 < Nn);      // 510 even -> pair fully valid or invalid
  for (int h = 0; h < 4; h++) {
    float cw[18];
    #pragma unroll
    for (int q = 0; q < 18; q++) cw[q] = convw[h * 18 + q];
    const float cb = convb[h];
    const float sih = si[(b * 4 + h) * Nn + i];
    float v0 = NEG_INF, v1 = NEG_INF;
    if (act) {
      float conv0 = cb, conv1 = cb;
      #pragma unroll
      for (int di = 0; di < 3; di++) {
        float2 am01 = *(float2*)&amr[di][j0];
        float2 am23 = *(float2*)&amr[di][j0 + 2];
        float2 cz01 = *(float2*)&c3[di][j0];
        float2 cz23 = *(float2*)&c3[di][j0 + 2];
        conv0 = fmaf(cw[di*3+0], am01.x, conv0);
        conv0 = fmaf(cw[di*3+1], am01.y, conv0);
        conv0 = fmaf(cw[di*3+2], am23.x, conv0);
        conv1 = fmaf(cw[di*3+0], am01.y, conv1);
        conv1 = fmaf(cw[di*3+1], am23.x, conv1);
        conv1 = fmaf(cw[di*3+2], am23.y, conv1);
        conv0 = fmaf(cw[9+di*3+0], cz01.x, conv0);
        conv0 = fmaf(cw[9+di*3+1], cz01.y, conv0);
        conv0 = fmaf(cw[9+di*3+2], cz23.x, conv0);
        conv1 = fmaf(cw[9+di*3+0], cz01.y, conv1);
        conv1 = fmaf(cw[9+di*3+1], cz23.x, conv1);
        conv1 = fmaf(cw[9+di*3+2], cz23.y, conv1);
      }
      float2 sj2 = *(const float2*)&sj[(b * 4 + h) * Nn + j0];
      float e0 = sih + sj2.x;
      float e1 = sih + sj2.y;
      float l0 = (e0 >= 0.f) ? e0 : SLOPE * e0;
      float l1 = (e1 >= 0.f) ? e1 : SLOPE * e1;
      v0 = ALPHA_ * l0 + (1.f - ALPHA_) * conv0;
      v1 = ALPHA_ * l1 + (1.f - ALPHA_) * conv1;
    }
    float mx = fmaxf(v0, v1);
    mx = wredmax(mx);
    if ((t & 63) == 0) red[t >> 6] = mx;
    __syncthreads();
    mx = fmaxf(fmaxf(red[0], red[1]), fmaxf(red[2], red[3]));
    __syncthreads();
    float p0 = 0.f, p1 = 0.f, sum = 0.f;
    if (act) {
      p0 = __expf(v0 - mx);
      p1 = __expf(v1 - mx);
      sum = p0 + p1;
    }
    sum = wredsum(sum);
    if ((t & 63) == 0) red[t >> 6] = sum;
    __syncthreads();
    sum = red[0] + red[1] + red[2] + red[3];
    __syncthreads();
    float inv = 1.f / sum;
    if (act) {
      float2 w2 = make_float2(p0 * inv, p1 * inv);
      *(float2*)&A[((b * 4 + h) * Nn + i) * (size_t)Nn + j0] = w2;
    }
  }
}

// K3: out[b,n,d] = 0.25 * sum_h sum_m A[b,h,n,m]*xt[b,m,h,d]; then
// g = out@fcg_w + fcg_b; glu = g_a*sigmoid(g_b); y = LN(glu + x).
// Grid (16 rowtiles, 32 b). Block tile: 32 rows x 64 d, thread tile 2x4.
__global__ __launch_bounds__(256) void k3_out(const float* __restrict__ A,
                                              const float* __restrict__ xt,
                                              const float* __restrict__ x,
                                              const float* __restrict__ fcgw,
                                              const float* __restrict__ fcgb,
                                              const float* __restrict__ lng,
                                              const float* __restrict__ lnb,
                                              float* __restrict__ y) {
  __shared__ float Al[32][68];
  __shared__ float xtl[64][68];
  __shared__ float ol[32][64];
  __shared__ float gl[2][128];
  const int t = threadIdx.x;
  const int rt = blockIdx.x;
  const int b = blockIdx.y;
  const int tc = t & 15, tr = t >> 4;
  const int c0 = tc * 4;
  float acc[2][4] = {};
  for (int h = 0; h < 4; h++) {
    const float* Ah = A + ((b * 4 + h) * Nn + rt * 32) * (size_t)Nn;
    for (int mt = 0; mt < 8; mt++) {
      const int m0 = mt * 64;
      #pragma unroll
      for (int k = 0; k < 4; k++) {
        int f = t + k * 256;
        int r = f >> 5;
        int cm = (f & 31) * 2;
        int m = m0 + cm;
        float2 v = make_float2(0.f, 0.f);
        if ((rt * 32 + r) < Nn && m < Nn) v = *(const float2*)&Ah[r * Nn + m];
        *(float2*)&Al[r][cm] = v;
      }
      #pragma unroll
      for (int k = 0; k < 4; k++) {
        int f = t + k * 256;
        int mi = f >> 4;
        int c = (f & 15) * 4;
        int m = m0 + mi;
        float4 v = make_float4(0.f, 0.f, 0.f, 0.f);
        if (m < Nn) v = *(const float4*)&xt[(b * Nn + m) * HD_ + h * Dd + c];
        *(float4*)&xtl[mi][c] = v;
      }
      __syncthreads();
      #pragma unroll
      for (int m4 = 0; m4 < 16; m4++) {
        float4 a0 = *(float4*)&Al[tr][m4 * 4];
        float4 a1 = *(float4*)&Al[tr + 16][m4 * 4];
        #pragma unroll
        for (int kk = 0; kk < 4; kk++) {
          float4 xv = *(float4*)&xtl[m4 * 4 + kk][c0];
          float w0 = (&a0.x)[kk];
          float w1 = (&a1.x)[kk];
          acc[0][0] = fmaf(w0, xv.x, acc[0][0]);
          acc[0][1] = fmaf(w0, xv.y, acc[0][1]);
          acc[0][2] = fmaf(w0, xv.z, acc[0][2]);
          acc[0][3] = fmaf(w0, xv.w, acc[0][3]);
          acc[1][0] = fmaf(w1, xv.x, acc[1][0]);
          acc[1][1] = fmaf(w1, xv.y, acc[1][1]);
          acc[1][2] = fmaf(w1, xv.z, acc[1][2]);
          acc[1][3] = fmaf(w1, xv.w, acc[1][3]);
        }
      }
      __syncthreads();
    }
  }
  *(float4*)&ol[tr][c0] = make_float4(0.25f * acc[0][0], 0.25f * acc[0][1],
                                      0.25f * acc[0][2], 0.25f * acc[0][3]);
  *(float4*)&ol[tr + 16][c0] = make_float4(0.25f * acc[1][0], 0.25f * acc[1][1],
                                           0.25f * acc[1][2], 0.25f * acc[1][3]);
  __syncthreads();
  const int kk = t & 127;
  const int rg = t >> 7;
  for (int it = 0; it < 16; it++) {
    const int r = it * 2 + rg;
    const int row = rt * 32 + r;
    float g = fcgb[kk];
    #pragma unroll
    for (int d = 0; d < 64; d++) g = fmaf(ol[r][d], fcgw[d * 128 + kk], g);
    gl[rg][kk] = g;
    __syncthreads();
    if (kk < 64 && row < Nn) {
      float a = gl[rg][kk];
      float bb = gl[rg][kk + 64];
      float glu = a / (1.f + __expf(-bb));
      float yv = glu + x[(b * Nn + row) * Dd + kk];
      float mu = wredsum(yv) * (1.f / 64.f);
      float dv = yv - mu;
      float var = wredsum(dv * dv) * (1.f / 64.f);
      float o = dv * rsqrtf(var + LNEPS) * lng[kk] + lnb[kk];
      y[(b * Nn + row) * Dd + kk] = o;
    }
    __syncthreads();
  }
}

extern "C" void kernel_launch(void* const* d_in, const int* in_sizes, int n_in,
                              void* d_out, int out_size, void* d_ws, size_t ws_size,
                              hipStream_t stream) {
  const float* x      = (const float*)d_in[0];
  const float* causal = (const float*)d_in[1];
  const float* W      = (const float*)d_in[2];
  const float* attw   = (const float*)d_in[3];
  const float* convw  = (const float*)d_in[4];
  const float* convb  = (const float*)d_in[5];
  const float* fcgw   = (const float*)d_in[6];
  const float* fcgb   = (const float*)d_in[7];
  const float* lng    = (const float*)d_in[8];
  const float* lnb    = (const float*)d_in[9];

  float* ws = (float*)d_ws;
  float* xt = ws;                          // 32*510*256 = 4,177,920 floats
  float* si = xt + (size_t)Bz * Nn * HD_;  // 65,280 floats
  float* sj = si + (size_t)Bz * Hh * Nn;   // 65,280 floats

  float* yout = (float*)d_out;                    // 32*510*64 = 1,044,480
  float* Aout = yout + (size_t)Bz * Nn * Dd;      // 32*4*510*510

  k1_xt <<<dim3(16, Bz, 2), 256, 0, stream>>>(x, W, xt);
  k1b_s <<<(Bz * Hh * Nn) / 4, 256, 0, stream>>>(xt, attw, si, sj);
  k2_attn<<<dim3(Nn, Bz), 256, 0, stream>>>(si, sj, causal, convw, convb, Aout);
  k3_out<<<dim3(16, Bz), 256, 0, stream>>>(Aout, xt, x, fcgw, fcgb, lng, lnb, yout);
}

// Round 2
// 309.928 us; speedup vs baseline: 1.3245x; 1.3245x over previous
//
#include <hip/hip_runtime.h>

#define Bz 32
#define Nn 510
#define Dd 64
#define Hh 4
#define HD_ 256
#define Kpad 512
#define ALPHA_ 0.1f
#define LNEPS 1e-5f
#define SLOPE 0.01f
#define NEG_INF -3.0e38f

typedef __attribute__((ext_vector_type(8))) short short8;
typedef __attribute__((ext_vector_type(4))) float floatx4;

__device__ inline float wredsum(float v) {
  #pragma unroll
  for (int off = 32; off; off >>= 1) v += __shfl_xor(v, off, 64);
  return v;
}
__device__ inline float wredmax(float v) {
  #pragma unroll
  for (int off = 32; off; off >>= 1) v = fmaxf(v, __shfl_xor(v, off, 64));
  return v;
}
// float -> bf16 bits, round-to-nearest-even
__device__ inline unsigned short f2bf(float f) {
  unsigned int u = __float_as_uint(f);
  unsigned int r = (u + 0x7fffu + ((u >> 16) & 1u)) >> 16;
  return (unsigned short)r;
}

// K1: xt = x@W; writes xtT bf16 [b][h][d][m(512 padded)] and si/sj (fused k1b).
// Grid (16 rowtiles, 32 b, 2 colhalves), 256 thr.
__global__ __launch_bounds__(256) void k1_xt(const float* __restrict__ x,
                                             const float* __restrict__ W,
                                             const float* __restrict__ attw,
                                             unsigned short* __restrict__ xtT,
                                             float* __restrict__ si,
                                             float* __restrict__ sj) {
  __shared__ float Wl[64][132];
  __shared__ float xr[32][68];
  const int t = threadIdx.x;
  const int rt = blockIdx.x;
  const int b = blockIdx.y;
  const int ch = blockIdx.z;
  #pragma unroll
  for (int k = 0; k < 8; k++) {
    int f = t + k * 256;
    int kr = f >> 5;
    int c = (f & 31) * 4;
    float4 v = *(const float4*)&W[kr * HD_ + ch * 128 + c];
    *(float4*)&Wl[kr][c] = v;
  }
  #pragma unroll
  for (int k = 0; k < 2; k++) {
    int f = t + k * 256;
    int r = f >> 4;
    int c = (f & 15) * 4;
    int row = rt * 32 + r;
    float4 v = make_float4(0.f, 0.f, 0.f, 0.f);
    if (row < Nn) v = *(const float4*)&x[(b * Nn + row) * Dd + c];
    *(float4*)&xr[r][c] = v;
  }
  __syncthreads();
  const int tr = t >> 5, tc = t & 31;
  const int rb = tr * 4, c0 = tc * 4;
  float acc[4][4] = {};
  #pragma unroll
  for (int k4 = 0; k4 < 16; k4++) {
    float4 xv[4];
    #pragma unroll
    for (int r = 0; r < 4; r++) xv[r] = *(float4*)&xr[rb + r][k4 * 4];
    #pragma unroll
    for (int kk = 0; kk < 4; kk++) {
      float4 wv = *(float4*)&Wl[k4 * 4 + kk][c0];
      #pragma unroll
      for (int r = 0; r < 4; r++) {
        float xs = (&xv[r].x)[kk];
        acc[r][0] = fmaf(xs, wv.x, acc[r][0]);
        acc[r][1] = fmaf(xs, wv.y, acc[r][1]);
        acc[r][2] = fmaf(xs, wv.z, acc[r][2]);
        acc[r][3] = fmaf(xs, wv.w, acc[r][3]);
      }
    }
  }
  const int colbase = ch * 128 + c0;
  const int h = colbase >> 6;       // all 4 cols in same head
  const int dd = colbase & 63;
  const int m0r = rt * 32 + rb;
  // xtT bf16 transposed store
  #pragma unroll
  for (int cc = 0; cc < 4; cc++) {
    unsigned short* p = &xtT[((size_t)(b * 4 + h) * 64 + (dd + cc)) * Kpad + m0r];
    if (m0r + 3 < Nn) {
      ushort4 u;
      u.x = f2bf(acc[0][cc]); u.y = f2bf(acc[1][cc]);
      u.z = f2bf(acc[2][cc]); u.w = f2bf(acc[3][cc]);
      *(ushort4*)p = u;
    } else {
      #pragma unroll
      for (int r = 0; r < 4; r++) if (m0r + r < Nn) p[r] = f2bf(acc[r][cc]);
    }
  }
  // fused si/sj: dot over this head's 64 cols, partial over our 4 cols,
  // reduce across the 16 threads sharing (row group, head).
  float w1v[4], w2v[4];
  #pragma unroll
  for (int cc = 0; cc < 4; cc++) {
    w1v[cc] = attw[h * 128 + dd + cc];
    w2v[cc] = attw[h * 128 + 64 + dd + cc];
  }
  #pragma unroll
  for (int r = 0; r < 4; r++) {
    float p1 = acc[r][0] * w1v[0] + acc[r][1] * w1v[1] +
               acc[r][2] * w1v[2] + acc[r][3] * w1v[3];
    float p2 = acc[r][0] * w2v[0] + acc[r][1] * w2v[1] +
               acc[r][2] * w2v[2] + acc[r][3] * w2v[3];
    #pragma unroll
    for (int off = 1; off <= 8; off <<= 1) {
      p1 += __shfl_xor(p1, off, 64);
      p2 += __shfl_xor(p2, off, 64);
    }
    if ((tc & 15) == 0) {
      int row = m0r + r;
      if (row < Nn) {
        si[(b * 4 + h) * Nn + row] = p1;
        sj[(b * 4 + h) * Nn + row] = p2;
      }
    }
  }
}

// K2: one block per (b,i); wave w = head; lane owns 8 contiguous j.
__global__ __launch_bounds__(256) void k2_attn(const float* __restrict__ si,
                                               const float* __restrict__ sj,
                                               const float* __restrict__ causal,
                                               const float* __restrict__ convw,
                                               const float* __restrict__ convb,
                                               float* __restrict__ A) {
  __shared__ float amr[3][520];
  __shared__ float c3[3][520];
  const int t = threadIdx.x;
  const int i = blockIdx.x;
  const int b = blockIdx.y;
  for (int e = t; e < 3 * 520; e += 256) {
    int row = e / 520;
    int jj = e - row * 520;
    int iq = i + row - 1;
    int j = jj - 1;
    float am = 0.f, cz = 0.f;
    if (jj < 512 && iq >= 0 && iq < Nn && j >= 0 && j < Nn) {
      float s = 0.f;
      #pragma unroll
      for (int hh = 0; hh < 4; hh++) {
        float e2 = si[(b * 4 + hh) * Nn + iq] + sj[(b * 4 + hh) * Nn + j];
        s += (e2 >= 0.f) ? e2 : SLOPE * e2;
      }
      am = 0.25f * s;
      cz = causal[iq * Nn + j];
    }
    amr[row][jj] = am;
    c3[row][jj] = cz;
  }
  __syncthreads();
  const int h = t >> 6;
  const int lane = t & 63;
  const int j0 = lane * 8;
  const int bh = b * 4 + h;
  const float sih = si[bh * Nn + i];
  float cw[18];
  #pragma unroll
  for (int q = 0; q < 18; q++) cw[q] = convw[h * 18 + q];
  float conv[8];
  const float cb = convb[h];
  #pragma unroll
  for (int e = 0; e < 8; e++) conv[e] = cb;
  #pragma unroll
  for (int di = 0; di < 3; di++) {
    float ta[12], tcc[12];
    *(float4*)&ta[0] = *(float4*)&amr[di][j0];
    *(float4*)&ta[4] = *(float4*)&amr[di][j0 + 4];
    *(float4*)&ta[8] = *(float4*)&amr[di][j0 + 8];
    *(float4*)&tcc[0] = *(float4*)&c3[di][j0];
    *(float4*)&tcc[4] = *(float4*)&c3[di][j0 + 4];
    *(float4*)&tcc[8] = *(float4*)&c3[di][j0 + 8];
    float w0 = cw[di * 3], w1 = cw[di * 3 + 1], w2 = cw[di * 3 + 2];
    float u0 = cw[9 + di * 3], u1 = cw[9 + di * 3 + 1], u2 = cw[9 + di * 3 + 2];
    #pragma unroll
    for (int e = 0; e < 8; e++) {
      float cv = conv[e];
      cv = fmaf(w0, ta[e], cv);
      cv = fmaf(w1, ta[e + 1], cv);
      cv = fmaf(w2, ta[e + 2], cv);
      cv = fmaf(u0, tcc[e], cv);
      cv = fmaf(u1, tcc[e + 1], cv);
      cv = fmaf(u2, tcc[e + 2], cv);
      conv[e] = cv;
    }
  }
  float sjv[8];
  {
    const float* sp = &sj[bh * Nn + j0];
    *(float2*)&sjv[0] = *(const float2*)&sp[0];
    *(float2*)&sjv[2] = *(const float2*)&sp[2];
    *(float2*)&sjv[4] = *(const float2*)&sp[4];
    // last pair may be OOB for lane 63 (j=510,511): sj has >=16 floats pad
    *(float2*)&sjv[6] = *(const float2*)&sp[6];
  }
  float v[8];
  float mx = NEG_INF;
  #pragma unroll
  for (int e = 0; e < 8; e++) {
    float ee = sih + sjv[e];
    float l = (ee >= 0.f) ? ee : SLOPE * ee;
    float val = ALPHA_ * l + (1.0f - ALPHA_) * conv[e];
    v[e] = (j0 + e < Nn) ? val : NEG_INF;
    mx = fmaxf(mx, v[e]);
  }
  mx = wredmax(mx);
  float p[8], s = 0.f;
  #pragma unroll
  for (int e = 0; e < 8; e++) {
    p[e] = __expf(v[e] - mx);
    s += p[e];
  }
  s = wredsum(s);
  const float inv = 1.f / s;
  float* Ar = &A[((size_t)bh * Nn + i) * Nn];
  #pragma unroll
  for (int pr = 0; pr < 4; pr++) {
    if (j0 + 2 * pr + 1 < Nn) {
      float2 w2v = make_float2(p[2 * pr] * inv, p[2 * pr + 1] * inv);
      *(float2*)&Ar[j0 + 2 * pr] = w2v;
    }
  }
}

// K3: out = 0.25*sum_h A_h @ xt_h via bf16 MFMA, fused fcg/GLU/residual/LN.
// Grid (16 rowtiles of 32, 32 b), 256 thr = 4 waves; wave tile 16x32.
__global__ __launch_bounds__(256) void k3_out(const float* __restrict__ A,
                                              const unsigned short* __restrict__ xtT,
                                              const float* __restrict__ x,
                                              const float* __restrict__ fcgw,
                                              const float* __restrict__ fcgb,
                                              const float* __restrict__ lng,
                                              const float* __restrict__ lnb,
                                              float* __restrict__ y) {
  __shared__ unsigned short Asub[32 * 72];
  __shared__ unsigned short Xsub[64 * 72];
  __shared__ float ol[32][64];
  __shared__ float gl[2][128];
  const int t = threadIdx.x;
  const int n0 = blockIdx.x * 32;
  const int b = blockIdx.y;
  const int w = t >> 6, lane = t & 63;
  const int quad = lane >> 4, l16 = lane & 15;
  const int wr = (w & 1) * 16;
  const int wc = (w >> 1) * 32;
  const int ar = t >> 3;            // A staging row 0..31
  const int amc = (t & 7) * 8;      // A staging m-offset
  const int xd = t >> 2;            // X staging d 0..63
  const int xmc = (t & 3) * 16;     // X staging m-offset
  floatx4 acc0 = {0.f, 0.f, 0.f, 0.f};
  floatx4 acc1 = {0.f, 0.f, 0.f, 0.f};
  for (int h = 0; h < 4; h++) {
    const float* Ab = &A[((size_t)(b * 4 + h) * Nn + n0) * Nn];
    const unsigned short* Xb = &xtT[(size_t)(b * 4 + h) * 64 * Kpad];
    for (int kt = 0; kt < 8; kt++) {
      const int m0 = kt * 64;
      __syncthreads();
      {
        int n = n0 + ar;
        int m = m0 + amc;
        float av[8] = {0.f, 0.f, 0.f, 0.f, 0.f, 0.f, 0.f, 0.f};
        if (n < Nn) {
          const float* src = &Ab[(size_t)ar * Nn + m];
          if (m + 7 < Nn) {
            #pragma unroll
            for (int q = 0; q < 4; q++) *(float2*)&av[2 * q] = *(const float2*)&src[2 * q];
          } else {
            int lim = Nn - m;
            #pragma unroll
            for (int q = 0; q < 8; q++) if (q < lim) av[q] = src[q];
          }
        }
        short8 as;
        #pragma unroll
        for (int q = 0; q < 8; q++) as[q] = (short)f2bf(av[q]);
        *(short8*)&Asub[ar * 72 + amc] = as;
        const unsigned short* xs = &Xb[(size_t)xd * Kpad + m0 + xmc];
        short8 x0 = *(const short8*)&xs[0];
        short8 x1 = *(const short8*)&xs[8];
        *(short8*)&Xsub[xd * 72 + xmc] = x0;
        *(short8*)&Xsub[xd * 72 + xmc + 8] = x1;
      }
      __syncthreads();
      #pragma unroll
      for (int ks = 0; ks < 2; ks++) {
        short8 af = *(short8*)&Asub[(wr + l16) * 72 + ks * 32 + quad * 8];
        short8 b0 = *(short8*)&Xsub[(wc + l16) * 72 + ks * 32 + quad * 8];
        short8 b1 = *(short8*)&Xsub[(wc + 16 + l16) * 72 + ks * 32 + quad * 8];
        acc0 = __builtin_amdgcn_mfma_f32_16x16x32_bf16(af, b0, acc0, 0, 0, 0);
        acc1 = __builtin_amdgcn_mfma_f32_16x16x32_bf16(af, b1, acc1, 0, 0, 0);
      }
    }
  }
  __syncthreads();
  #pragma unroll
  for (int reg = 0; reg < 4; reg++) {
    ol[wr + quad * 4 + reg][wc + l16] = 0.25f * acc0[reg];
    ol[wr + quad * 4 + reg][wc + 16 + l16] = 0.25f * acc1[reg];
  }
  __syncthreads();
  const int kk = t & 127;
  const int rg = t >> 7;
  for (int it = 0; it < 16; it++) {
    const int r = it * 2 + rg;
    const int row = n0 + r;
    float g = fcgb[kk];
    #pragma unroll
    for (int d = 0; d < 64; d++) g = fmaf(ol[r][d], fcgw[d * 128 + kk], g);
    gl[rg][kk] = g;
    __syncthreads();
    if (kk < 64 && row < Nn) {
      float a = gl[rg][kk];
      float bb = gl[rg][kk + 64];
      float glu = a / (1.f + __expf(-bb));
      float yv = glu + x[(b * Nn + row) * Dd + kk];
      float mu = wredsum(yv) * (1.f / 64.f);
      float dv = yv - mu;
      float var = wredsum(dv * dv) * (1.f / 64.f);
      float o = dv * rsqrtf(var + LNEPS) * lng[kk] + lnb[kk];
      y[(b * Nn + row) * Dd + kk] = o;
    }
    __syncthreads();
  }
}

extern "C" void kernel_launch(void* const* d_in, const int* in_sizes, int n_in,
                              void* d_out, int out_size, void* d_ws, size_t ws_size,
                              hipStream_t stream) {
  const float* x      = (const float*)d_in[0];
  const float* causal = (const float*)d_in[1];
  const float* W      = (const float*)d_in[2];
  const float* attw   = (const float*)d_in[3];
  const float* convw  = (const float*)d_in[4];
  const float* convb  = (const float*)d_in[5];
  const float* fcgw   = (const float*)d_in[6];
  const float* fcgb   = (const float*)d_in[7];
  const float* lng    = (const float*)d_in[8];
  const float* lnb    = (const float*)d_in[9];

  float* ws = (float*)d_ws;
  float* si = ws;                                  // 65,280 floats
  float* sj = si + (size_t)Bz * Hh * Nn;           // 65,280 floats (+16 pad)
  unsigned short* xtT = (unsigned short*)(sj + (size_t)Bz * Hh * Nn + 16);
  size_t xtT_bytes = (size_t)Bz * Hh * Dd * Kpad * sizeof(unsigned short); // 8.4 MB

  float* yout = (float*)d_out;                     // 32*510*64
  float* Aout = yout + (size_t)Bz * Nn * Dd;       // 32*4*510*510

  hipMemsetAsync(xtT, 0, xtT_bytes, stream);
  k1_xt <<<dim3(16, Bz, 2), 256, 0, stream>>>(x, W, attw, xtT, si, sj);
  k2_attn<<<dim3(Nn, Bz), 256, 0, stream>>>(si, sj, causal, convw, convb, Aout);
  k3_out<<<dim3(16, Bz), 256, 0, stream>>>(Aout, xtT, x, fcgw, fcgb, lng, lnb, yout);
}

// Round 3
// 308.456 us; speedup vs baseline: 1.3308x; 1.0048x over previous
//
#include <hip/hip_runtime.h>

#define Bz 32
#define Nn 510
#define Dd 64
#define Hh 4
#define HD_ 256
#define Kpad 512
#define ALPHA_ 0.1f
#define LNEPS 1e-5f
#define SLOPE 0.01f
#define NEG_INF -3.0e38f

typedef __attribute__((ext_vector_type(8))) short short8;
typedef __attribute__((ext_vector_type(4))) float floatx4;

__device__ inline float wredsum(float v) {
  #pragma unroll
  for (int off = 32; off; off >>= 1) v += __shfl_xor(v, off, 64);
  return v;
}
__device__ inline float wredmax(float v) {
  #pragma unroll
  for (int off = 32; off; off >>= 1) v = fmaxf(v, __shfl_xor(v, off, 64));
  return v;
}
__device__ inline unsigned short f2bf(float f) {
  unsigned int u = __float_as_uint(f);
  unsigned int r = (u + 0x7fffu + ((u >> 16) & 1u)) >> 16;
  return (unsigned short)r;
}

// K1: xt = x@W; writes xtT bf16 [b][h][d][m(512 padded)] and si/sj (fused).
__global__ __launch_bounds__(256) void k1_xt(const float* __restrict__ x,
                                             const float* __restrict__ W,
                                             const float* __restrict__ attw,
                                             unsigned short* __restrict__ xtT,
                                             float* __restrict__ si,
                                             float* __restrict__ sj) {
  __shared__ float Wl[64][132];
  __shared__ float xr[32][68];
  const int t = threadIdx.x;
  const int rt = blockIdx.x;
  const int b = blockIdx.y;
  const int ch = blockIdx.z;
  #pragma unroll
  for (int k = 0; k < 8; k++) {
    int f = t + k * 256;
    int kr = f >> 5;
    int c = (f & 31) * 4;
    float4 v = *(const float4*)&W[kr * HD_ + ch * 128 + c];
    *(float4*)&Wl[kr][c] = v;
  }
  #pragma unroll
  for (int k = 0; k < 2; k++) {
    int f = t + k * 256;
    int r = f >> 4;
    int c = (f & 15) * 4;
    int row = rt * 32 + r;
    float4 v = make_float4(0.f, 0.f, 0.f, 0.f);
    if (row < Nn) v = *(const float4*)&x[(b * Nn + row) * Dd + c];
    *(float4*)&xr[r][c] = v;
  }
  __syncthreads();
  const int tr = t >> 5, tc = t & 31;
  const int rb = tr * 4, c0 = tc * 4;
  float acc[4][4] = {};
  #pragma unroll
  for (int k4 = 0; k4 < 16; k4++) {
    float4 xv[4];
    #pragma unroll
    for (int r = 0; r < 4; r++) xv[r] = *(float4*)&xr[rb + r][k4 * 4];
    #pragma unroll
    for (int kk = 0; kk < 4; kk++) {
      float4 wv = *(float4*)&Wl[k4 * 4 + kk][c0];
      #pragma unroll
      for (int r = 0; r < 4; r++) {
        float xs = (&xv[r].x)[kk];
        acc[r][0] = fmaf(xs, wv.x, acc[r][0]);
        acc[r][1] = fmaf(xs, wv.y, acc[r][1]);
        acc[r][2] = fmaf(xs, wv.z, acc[r][2]);
        acc[r][3] = fmaf(xs, wv.w, acc[r][3]);
      }
    }
  }
  const int colbase = ch * 128 + c0;
  const int h = colbase >> 6;
  const int dd = colbase & 63;
  const int m0r = rt * 32 + rb;
  #pragma unroll
  for (int cc = 0; cc < 4; cc++) {
    unsigned short* p = &xtT[((size_t)(b * 4 + h) * 64 + (dd + cc)) * Kpad + m0r];
    if (m0r + 3 < Nn) {
      ushort4 u;
      u.x = f2bf(acc[0][cc]); u.y = f2bf(acc[1][cc]);
      u.z = f2bf(acc[2][cc]); u.w = f2bf(acc[3][cc]);
      *(ushort4*)p = u;
    } else {
      #pragma unroll
      for (int r = 0; r < 4; r++) if (m0r + r < Nn) p[r] = f2bf(acc[r][cc]);
    }
  }
  float w1v[4], w2v[4];
  #pragma unroll
  for (int cc = 0; cc < 4; cc++) {
    w1v[cc] = attw[h * 128 + dd + cc];
    w2v[cc] = attw[h * 128 + 64 + dd + cc];
  }
  #pragma unroll
  for (int r = 0; r < 4; r++) {
    float p1 = acc[r][0] * w1v[0] + acc[r][1] * w1v[1] +
               acc[r][2] * w1v[2] + acc[r][3] * w1v[3];
    float p2 = acc[r][0] * w2v[0] + acc[r][1] * w2v[1] +
               acc[r][2] * w2v[2] + acc[r][3] * w2v[3];
    #pragma unroll
    for (int off = 1; off <= 8; off <<= 1) {
      p1 += __shfl_xor(p1, off, 64);
      p2 += __shfl_xor(p2, off, 64);
    }
    if ((tc & 15) == 0) {
      int row = m0r + r;
      if (row < Nn) {
        si[(b * 4 + h) * Nn + row] = p1;
        sj[(b * 4 + h) * Nn + row] = p2;
      }
    }
  }
}

// K2: block = (b, itile of 8 rows). Transposed LDS: elem j -> [j&7][(j>>3)+1]
// (conflict-free stride-1-across-lanes reads). Wave = one (i,h) pair per iter.
__global__ __launch_bounds__(256) void k2_attn(const float* __restrict__ si,
                                               const float* __restrict__ sj,
                                               const float* __restrict__ causal,
                                               const float* __restrict__ convw,
                                               const float* __restrict__ convb,
                                               float* __restrict__ A) {
  __shared__ float am_t[10 * 8 * 68];   // [row r][e=j&7][c=(j>>3)+1], c in 0..65
  __shared__ float cz_t[10 * 8 * 68];
  __shared__ float sjl[4 * 8 * 68];     // [h][e][c=(j>>3)+1]
  __shared__ float sil[4][12];          // [h][r], iq = i0 + r - 1
  const int t = threadIdx.x;
  const int i0 = blockIdx.x * 8;
  const int b = blockIdx.y;
  // pass A: sil, sjl, boundary zeros of am_t/cz_t
  if (t < 40) {
    int h = t / 10, r = t % 10;
    int iq = i0 + r - 1;
    sil[h][r] = (iq >= 0 && iq < Nn) ? si[(b * 4 + h) * Nn + iq] : 0.f;
  }
  if (t >= 64 && t < 224) {
    int q = t - 64;
    int r = q >> 4, rem = q & 15;
    int e = rem >> 1, side = rem & 1;
    int idx = (r * 8 + e) * 68 + side * 65;
    am_t[idx] = 0.f;
    cz_t[idx] = 0.f;
  }
  for (int f = t; f < 2048; f += 256) {
    int h = f >> 9, j = f & 511;
    float v = (j < Nn) ? sj[(b * 4 + h) * Nn + j] : 0.f;
    sjl[(h * 8 + (j & 7)) * 68 + (j >> 3) + 1] = v;
  }
  __syncthreads();
  // pass B: A_mean + causal staging (transposed)
  for (int f = t; f < 5120; f += 256) {
    int r = f >> 9, j = f & 511;
    int iq = i0 + r - 1;
    float am = 0.f, cz = 0.f;
    if (iq >= 0 && iq < Nn && j < Nn) {
      float s = 0.f;
      #pragma unroll
      for (int h = 0; h < 4; h++) {
        float e2 = sil[h][r] + sjl[(h * 8 + (j & 7)) * 68 + (j >> 3) + 1];
        s += (e2 >= 0.f) ? e2 : SLOPE * e2;
      }
      am = 0.25f * s;
      cz = causal[iq * Nn + j];
    }
    int idx = (r * 8 + (j & 7)) * 68 + (j >> 3) + 1;
    am_t[idx] = am;
    cz_t[idx] = cz;
  }
  __syncthreads();
  const int w = t >> 6, L = t & 63;
  const int j0 = L * 8;
  for (int pp = w; pp < 32; pp += 4) {
    const int il = pp >> 2, h = pp & 3;
    const int i = i0 + il;
    if (i >= Nn) continue;
    const int bh = b * 4 + h;
    const float sih = sil[h][il + 1];
    float cw[18];
    #pragma unroll
    for (int q = 0; q < 18; q++) cw[q] = convw[h * 18 + q];
    const float cb = convb[h];
    float conv[8];
    #pragma unroll
    for (int e = 0; e < 8; e++) conv[e] = cb;
    #pragma unroll
    for (int r3 = 0; r3 < 3; r3++) {
      const float* ba = &am_t[((il + r3) * 8) * 68];
      const float* bc = &cz_t[((il + r3) * 8) * 68];
      float a[10], c[10];
      a[0] = ba[7 * 68 + L];       // j0-1
      c[0] = bc[7 * 68 + L];
      #pragma unroll
      for (int e = 0; e < 8; e++) {
        a[1 + e] = ba[e * 68 + L + 1];
        c[1 + e] = bc[e * 68 + L + 1];
      }
      a[9] = ba[0 * 68 + L + 2];   // j0+8
      c[9] = bc[0 * 68 + L + 2];
      float w0 = cw[r3 * 3], w1 = cw[r3 * 3 + 1], w2 = cw[r3 * 3 + 2];
      float u0 = cw[9 + r3 * 3], u1 = cw[9 + r3 * 3 + 1], u2 = cw[9 + r3 * 3 + 2];
      #pragma unroll
      for (int e = 0; e < 8; e++) {
        float cv = conv[e];
        cv = fmaf(w0, a[e], cv);
        cv = fmaf(w1, a[e + 1], cv);
        cv = fmaf(w2, a[e + 2], cv);
        cv = fmaf(u0, c[e], cv);
        cv = fmaf(u1, c[e + 1], cv);
        cv = fmaf(u2, c[e + 2], cv);
        conv[e] = cv;
      }
    }
    float v[8];
    float mx = NEG_INF;
    #pragma unroll
    for (int e = 0; e < 8; e++) {
      float ee = sih + sjl[(h * 8 + e) * 68 + L + 1];
      float l = (ee >= 0.f) ? ee : SLOPE * ee;
      float val = ALPHA_ * l + (1.0f - ALPHA_) * conv[e];
      v[e] = (j0 + e < Nn) ? val : NEG_INF;
      mx = fmaxf(mx, v[e]);
    }
    mx = wredmax(mx);
    float p[8], s = 0.f;
    #pragma unroll
    for (int e = 0; e < 8; e++) {
      p[e] = __expf(v[e] - mx);
      s += p[e];
    }
    s = wredsum(s);
    const float inv = 1.f / s;
    #pragma unroll
    for (int e = 0; e < 8; e++) p[e] *= inv;
    float* Ar = &A[((size_t)bh * Nn + i) * Nn + j0];
    *(float4*)&Ar[0] = make_float4(p[0], p[1], p[2], p[3]);
    if (L < 63) {
      *(float4*)&Ar[4] = make_float4(p[4], p[5], p[6], p[7]);
    } else {
      *(float2*)&Ar[4] = make_float2(p[4], p[5]);
    }
  }
}

// K3: out = 0.25*sum_h A_h @ xt_h via bf16 MFMA, fused fcg/GLU/residual/LN.
// Grid (32 rowtiles of 16, 32 b), 256 thr = 4 waves; wave = 16x16 col-slice.
__global__ __launch_bounds__(256) void k3_out(const float* __restrict__ A,
                                              const unsigned short* __restrict__ xtT,
                                              const float* __restrict__ x,
                                              const float* __restrict__ fcgw,
                                              const float* __restrict__ fcgb,
                                              const float* __restrict__ lng,
                                              const float* __restrict__ lnb,
                                              float* __restrict__ y) {
  __shared__ unsigned short Asub[16 * 72];
  __shared__ unsigned short Xsub[64 * 72];
  __shared__ float ol[16][64];
  __shared__ float gl[2][128];
  const int t = threadIdx.x;
  const int n0 = blockIdx.x * 16;
  const int b = blockIdx.y;
  const int w = t >> 6, lane = t & 63;
  const int quad = lane >> 4, l16 = lane & 15;
  const int wc = w * 16;
  const int ar = t >> 4;          // A staging row 0..15
  const int amc = (t & 15) * 4;   // A staging m-offset
  const int xd = t >> 2;          // X staging d 0..63
  const int xmc = (t & 3) * 16;   // X staging m-offset
  floatx4 acc = {0.f, 0.f, 0.f, 0.f};
  for (int h = 0; h < 4; h++) {
    const float* Ab = &A[((size_t)(b * 4 + h) * Nn + n0) * Nn];
    const unsigned short* Xb = &xtT[(size_t)(b * 4 + h) * 64 * Kpad];
    for (int kt = 0; kt < 8; kt++) {
      const int m0 = kt * 64;
      __syncthreads();
      {
        int n = n0 + ar;
        int m = m0 + amc;
        float av[4] = {0.f, 0.f, 0.f, 0.f};
        if (n < Nn) {
          const float* src = &Ab[(size_t)ar * Nn + m];
          if (m + 3 < Nn) {
            *(float4*)av = *(const float4*)src;
          } else {
            int lim = Nn - m;
            #pragma unroll
            for (int q = 0; q < 4; q++) if (q < lim) av[q] = src[q];
          }
        }
        ushort4 u;
        u.x = f2bf(av[0]); u.y = f2bf(av[1]);
        u.z = f2bf(av[2]); u.w = f2bf(av[3]);
        *(ushort4*)&Asub[ar * 72 + amc] = u;
        const unsigned short* xs = &Xb[(size_t)xd * Kpad + m0 + xmc];
        short8 x0 = *(const short8*)&xs[0];
        short8 x1 = *(const short8*)&xs[8];
        *(short8*)&Xsub[xd * 72 + xmc] = x0;
        *(short8*)&Xsub[xd * 72 + xmc + 8] = x1;
      }
      __syncthreads();
      #pragma unroll
      for (int ks = 0; ks < 2; ks++) {
        short8 af = *(short8*)&Asub[l16 * 72 + ks * 32 + quad * 8];
        short8 bf = *(short8*)&Xsub[(wc + l16) * 72 + ks * 32 + quad * 8];
        acc = __builtin_amdgcn_mfma_f32_16x16x32_bf16(af, bf, acc, 0, 0, 0);
      }
    }
  }
  __syncthreads();
  #pragma unroll
  for (int reg = 0; reg < 4; reg++) {
    ol[quad * 4 + reg][wc + l16] = 0.25f * acc[reg];
  }
  __syncthreads();
  const int kk = t & 127;
  const int rg = t >> 7;
  for (int it = 0; it < 8; it++) {
    const int r = it * 2 + rg;
    const int row = n0 + r;
    float g = fcgb[kk];
    #pragma unroll
    for (int d = 0; d < 64; d++) g = fmaf(ol[r][d], fcgw[d * 128 + kk], g);
    gl[rg][kk] = g;
    __syncthreads();
    if (kk < 64 && row < Nn) {
      float a = gl[rg][kk];
      float bb = gl[rg][kk + 64];
      float glu = a / (1.f + __expf(-bb));
      float yv = glu + x[(b * Nn + row) * Dd + kk];
      float mu = wredsum(yv) * (1.f / 64.f);
      float dv = yv - mu;
      float var = wredsum(dv * dv) * (1.f / 64.f);
      float o = dv * rsqrtf(var + LNEPS) * lng[kk] + lnb[kk];
      y[(b * Nn + row) * Dd + kk] = o;
    }
    __syncthreads();
  }
}

extern "C" void kernel_launch(void* const* d_in, const int* in_sizes, int n_in,
                              void* d_out, int out_size, void* d_ws, size_t ws_size,
                              hipStream_t stream) {
  const float* x      = (const float*)d_in[0];
  const float* causal = (const float*)d_in[1];
  const float* W      = (const float*)d_in[2];
  const float* attw   = (const float*)d_in[3];
  const float* convw  = (const float*)d_in[4];
  const float* convb  = (const float*)d_in[5];
  const float* fcgw   = (const float*)d_in[6];
  const float* fcgb   = (const float*)d_in[7];
  const float* lng    = (const float*)d_in[8];
  const float* lnb    = (const float*)d_in[9];

  float* ws = (float*)d_ws;
  float* si = ws;                                  // 65,280 floats
  float* sj = si + (size_t)Bz * Hh * Nn;           // 65,280 floats (+16 pad)
  unsigned short* xtT = (unsigned short*)(sj + (size_t)Bz * Hh * Nn + 16);
  size_t xtT_bytes = (size_t)Bz * Hh * Dd * Kpad * sizeof(unsigned short); // 8.4 MB

  float* yout = (float*)d_out;                     // 32*510*64
  float* Aout = yout + (size_t)Bz * Nn * Dd;       // 32*4*510*510

  hipMemsetAsync(xtT, 0, xtT_bytes, stream);
  k1_xt <<<dim3(16, Bz, 2), 256, 0, stream>>>(x, W, attw, xtT, si, sj);
  k2_attn<<<dim3(64, Bz), 256, 0, stream>>>(si, sj, causal, convw, convb, Aout);
  k3_out <<<dim3(32, Bz), 256, 0, stream>>>(Aout, xtT, x, fcgw, fcgb, lng, lnb, yout);
}